// Round 1
// baseline (489.641 us; speedup 1.0000x reference)
//
#include <hip/hip_runtime.h>

#define B_  8
#define SQ_ 2048
#define SK_ 2048
#define D_  128

// ---------------------------------------------------------------------------
// K1: qw[b,q,dk] = sum_dq query[b,q,dq] * W[dq,dk]
// grid: (B*SQ)/64 = 256 blocks, 256 threads. W fully in LDS (64 KB).
// Each thread: 4 rows x 8 cols, q rows chunk-cached in registers (L1-backed).
// ---------------------------------------------------------------------------
__global__ __launch_bounds__(256) void k1_qw(const float* __restrict__ q,
                                             const float* __restrict__ w,
                                             float* __restrict__ qw) {
    __shared__ float Ws[D_ * D_];  // [d][c] natural layout
    const int tid = threadIdx.x;
    const int rowbase = blockIdx.x * 64;

    #pragma unroll
    for (int t = 0; t < 16; ++t) {
        int i4 = t * 256 + tid;
        ((float4*)Ws)[i4] = ((const float4*)w)[i4];
    }
    __syncthreads();

    const int mg = tid >> 4, cg = tid & 15;
    const int c0 = cg * 8;
    const float* qrow[4];
    #pragma unroll
    for (int i = 0; i < 4; ++i)
        qrow[i] = q + (size_t)(rowbase + mg * 4 + i) * D_;

    float acc[4][8];
    #pragma unroll
    for (int i = 0; i < 4; ++i)
        #pragma unroll
        for (int j = 0; j < 8; ++j) acc[i][j] = 0.0f;

    for (int d0 = 0; d0 < D_; d0 += 16) {
        float qr[4][16];
        #pragma unroll
        for (int i = 0; i < 4; ++i)
            #pragma unroll
            for (int c4 = 0; c4 < 4; ++c4)
                *(float4*)&qr[i][c4 * 4] = *(const float4*)(qrow[i] + d0 + c4 * 4);
        #pragma unroll
        for (int dd = 0; dd < 16; ++dd) {
            const int d = d0 + dd;
            float4 w0 = *(const float4*)&Ws[d * D_ + c0];
            float4 w1 = *(const float4*)&Ws[d * D_ + c0 + 4];
            #pragma unroll
            for (int i = 0; i < 4; ++i) {
                float a = qr[i][dd];
                acc[i][0] += a * w0.x; acc[i][1] += a * w0.y;
                acc[i][2] += a * w0.z; acc[i][3] += a * w0.w;
                acc[i][4] += a * w1.x; acc[i][5] += a * w1.y;
                acc[i][6] += a * w1.z; acc[i][7] += a * w1.w;
            }
        }
    }

    #pragma unroll
    for (int i = 0; i < 4; ++i) {
        float* dst = qw + (size_t)(rowbase + mg * 4 + i) * D_ + c0;
        *(float4*)dst       = make_float4(acc[i][0], acc[i][1], acc[i][2], acc[i][3]);
        *(float4*)(dst + 4) = make_float4(acc[i][4], acc[i][5], acc[i][6], acc[i][7]);
    }
}

// XOR-swizzled 16B chunk addressing: element (r, d) of a [64][128] tile lives at
// r*128 + ((d/4 ^ ((r>>2)&7))*4 + d%4.  Keeps b128 reads <=2-way bank aliased.
__device__ __forceinline__ float4 lds_chunk(const float* buf, int r, int c) {
    int cs = c ^ ((r >> 2) & 7);
    return *(const float4*)&buf[r * 128 + cs * 4];
}

// ---------------------------------------------------------------------------
// K2: S[b,m,n] = sum_d qw[b,m,d] * key[b,n,d].  grid (32,32,8), 256 thr.
// K=128 staged fully in LDS (2 x 32 KB).  4x4 register tiles, float4 k-chunks.
// ---------------------------------------------------------------------------
__global__ __launch_bounds__(256) void k2_score(const float* __restrict__ qw,
                                                const float* __restrict__ key,
                                                float* __restrict__ S) {
    __shared__ float As[64 * 128];
    __shared__ float Bs[64 * 128];
    const int tid = threadIdx.x;
    const int b   = blockIdx.z;
    const int m0b = blockIdx.y * 64;
    const int n0b = blockIdx.x * 64;
    const float* Ag = qw  + ((size_t)b * SQ_ + m0b) * D_;
    const float* Bg = key + ((size_t)b * SK_ + n0b) * D_;

    #pragma unroll
    for (int t = 0; t < 8; ++t) {
        int l = t * 256 + tid;
        int r = l >> 5, c = l & 31;
        int cs = c ^ ((r >> 2) & 7);
        *(float4*)&As[r * 128 + cs * 4] = ((const float4*)(Ag + (size_t)r * D_))[c];
        *(float4*)&Bs[r * 128 + cs * 4] = ((const float4*)(Bg + (size_t)r * D_))[c];
    }
    __syncthreads();

    const int ty = tid >> 4, tx = tid & 15;
    const int m0 = ty * 4, n0 = tx * 4;
    float acc[4][4];
    #pragma unroll
    for (int i = 0; i < 4; ++i)
        #pragma unroll
        for (int j = 0; j < 4; ++j) acc[i][j] = 0.0f;

    for (int cc = 0; cc < 32; ++cc) {
        float4 a[4], bb[4];
        #pragma unroll
        for (int i = 0; i < 4; ++i) a[i] = lds_chunk(As, m0 + i, cc);
        #pragma unroll
        for (int j = 0; j < 4; ++j) bb[j] = lds_chunk(Bs, n0 + j, cc);
        #pragma unroll
        for (int i = 0; i < 4; ++i)
            #pragma unroll
            for (int j = 0; j < 4; ++j)
                acc[i][j] += a[i].x * bb[j].x + a[i].y * bb[j].y +
                             a[i].z * bb[j].z + a[i].w * bb[j].w;
    }

    #pragma unroll
    for (int i = 0; i < 4; ++i) {
        float4 o = make_float4(acc[i][0], acc[i][1], acc[i][2], acc[i][3]);
        *(float4*)&S[((size_t)b * SQ_ + m0b + m0 + i) * SK_ + n0b + n0] = o;
    }
}

// ---------------------------------------------------------------------------
// K3: row-wise softmax in place.  grid = B*SQ blocks (one row each), 256 thr.
// ---------------------------------------------------------------------------
__global__ __launch_bounds__(256) void k3_softmax(float* __restrict__ S) {
    const size_t base = (size_t)blockIdx.x * SK_;
    const int tid = threadIdx.x;
    float4* p = (float4*)(S + base);   // 512 float4 per row
    float4 x0 = p[tid];
    float4 x1 = p[tid + 256];

    float m = fmaxf(fmaxf(fmaxf(x0.x, x0.y), fmaxf(x0.z, x0.w)),
                    fmaxf(fmaxf(x1.x, x1.y), fmaxf(x1.z, x1.w)));
    #pragma unroll
    for (int off = 32; off; off >>= 1) m = fmaxf(m, __shfl_xor(m, off, 64));
    __shared__ float redm[4];
    if ((tid & 63) == 0) redm[tid >> 6] = m;
    __syncthreads();
    m = fmaxf(fmaxf(redm[0], redm[1]), fmaxf(redm[2], redm[3]));

    float4 e0, e1;
    e0.x = __expf(x0.x - m); e0.y = __expf(x0.y - m);
    e0.z = __expf(x0.z - m); e0.w = __expf(x0.w - m);
    e1.x = __expf(x1.x - m); e1.y = __expf(x1.y - m);
    e1.z = __expf(x1.z - m); e1.w = __expf(x1.w - m);
    float s = e0.x + e0.y + e0.z + e0.w + e1.x + e1.y + e1.z + e1.w;
    #pragma unroll
    for (int off = 32; off; off >>= 1) s += __shfl_xor(s, off, 64);
    __shared__ float reds[4];
    if ((tid & 63) == 0) reds[tid >> 6] = s;
    __syncthreads();
    s = reds[0] + reds[1] + reds[2] + reds[3];
    float inv = 1.0f / s;

    e0.x *= inv; e0.y *= inv; e0.z *= inv; e0.w *= inv;
    e1.x *= inv; e1.y *= inv; e1.z *= inv; e1.w *= inv;
    p[tid] = e0;
    p[tid + 256] = e1;
}

// ---------------------------------------------------------------------------
// K4: out[b,m,v] = sum_s weight[b,m,s] * value[b,s,v].
// grid (SQ/32, B) = 512 blocks, 256 thr.  M-tile 32, N=128 full, K-tile 64.
// Each thread: 2 rows x 8 cols.
// ---------------------------------------------------------------------------
__global__ __launch_bounds__(256) void k4_out(const float* __restrict__ W,
                                              const float* __restrict__ V,
                                              float* __restrict__ O) {
    __shared__ float Wt[32 * 68];   // pad 68: conflict-free scalar reads
    __shared__ float Vt[64 * 128];
    const int tid = threadIdx.x;
    const int b   = blockIdx.y;
    const int m0b = blockIdx.x * 32;
    const float* Wg = W + ((size_t)b * SQ_ + m0b) * SK_;
    const float* Vg = V + (size_t)b * SK_ * D_;
    const int mg = tid >> 4, ng = tid & 15;   // rows 2*mg..+1, cols 8*ng..+7

    float acc[2][8];
    #pragma unroll
    for (int i = 0; i < 2; ++i)
        #pragma unroll
        for (int j = 0; j < 8; ++j) acc[i][j] = 0.0f;

    for (int kt = 0; kt < SK_; kt += 64) {
        __syncthreads();
        #pragma unroll
        for (int t = 0; t < 2; ++t) {   // Wt: 32x64 = 512 float4
            int l = t * 256 + tid;
            int r = l >> 4, c4 = l & 15;
            float4 v = ((const float4*)(Wg + (size_t)r * SK_ + kt))[c4];
            *(float4*)&Wt[r * 68 + c4 * 4] = v;
        }
        #pragma unroll
        for (int t = 0; t < 8; ++t) {   // Vt: 64x128 = 2048 float4
            int l = t * 256 + tid;
            int r = l >> 5, c4 = l & 31;
            float4 v = ((const float4*)(Vg + (size_t)(kt + r) * D_))[c4];
            *(float4*)&Vt[r * 128 + c4 * 4] = v;
        }
        __syncthreads();

        for (int k = 0; k < 64; ++k) {
            float a0 = Wt[(2 * mg)     * 68 + k];
            float a1 = Wt[(2 * mg + 1) * 68 + k];
            float4 b0 = *(const float4*)&Vt[k * 128 + ng * 8];
            float4 b1 = *(const float4*)&Vt[k * 128 + ng * 8 + 4];
            acc[0][0] += a0 * b0.x; acc[0][1] += a0 * b0.y;
            acc[0][2] += a0 * b0.z; acc[0][3] += a0 * b0.w;
            acc[0][4] += a0 * b1.x; acc[0][5] += a0 * b1.y;
            acc[0][6] += a0 * b1.z; acc[0][7] += a0 * b1.w;
            acc[1][0] += a1 * b0.x; acc[1][1] += a1 * b0.y;
            acc[1][2] += a1 * b0.z; acc[1][3] += a1 * b0.w;
            acc[1][4] += a1 * b1.x; acc[1][5] += a1 * b1.y;
            acc[1][6] += a1 * b1.z; acc[1][7] += a1 * b1.w;
        }
    }

    #pragma unroll
    for (int i = 0; i < 2; ++i) {
        float* dst = O + ((size_t)b * SQ_ + m0b + 2 * mg + i) * D_ + ng * 8;
        *(float4*)dst       = make_float4(acc[i][0], acc[i][1], acc[i][2], acc[i][3]);
        *(float4*)(dst + 4) = make_float4(acc[i][4], acc[i][5], acc[i][6], acc[i][7]);
    }
}

extern "C" void kernel_launch(void* const* d_in, const int* in_sizes, int n_in,
                              void* d_out, int out_size, void* d_ws, size_t ws_size,
                              hipStream_t stream) {
    const float* q = (const float*)d_in[0];
    const float* k = (const float*)d_in[1];
    const float* v = (const float*)d_in[2];
    const float* w = (const float*)d_in[3];
    float* out    = (float*)d_out;                       // [B*SQ*D]
    float* weight = out + (size_t)B_ * SQ_ * D_;         // [B*SQ*SK]
    // qw scratch: reuse the out region (same size, dead until k4 overwrites it)
    float* qw = out;

    k1_qw<<<(B_ * SQ_) / 64, 256, 0, stream>>>(q, w, qw);
    k2_score<<<dim3(SK_ / 64, SQ_ / 64, B_), 256, 0, stream>>>(qw, k, weight);
    k3_softmax<<<B_ * SQ_, 256, 0, stream>>>(weight);
    k4_out<<<dim3(SQ_ / 32, B_), 256, 0, stream>>>(weight, v, out);
}

// Round 2
// 442.274 us; speedup vs baseline: 1.1071x; 1.1071x over previous
//
#include <hip/hip_runtime.h>

#define B_  8
#define SQ_ 2048
#define SK_ 2048
#define D_  128

typedef float  f32x4 __attribute__((ext_vector_type(4)));
typedef short  s16x8 __attribute__((ext_vector_type(8)));
typedef __bf16 b16x8 __attribute__((ext_vector_type(8)));

__device__ __forceinline__ f32x4 mfma16(s16x8 a, s16x8 b, f32x4 c) {
    return __builtin_amdgcn_mfma_f32_16x16x32_bf16(
        __builtin_bit_cast(b16x8, a), __builtin_bit_cast(b16x8, b), c, 0, 0, 0);
}

// truncate-to-bf16 pack of two floats (a -> low u16, b -> high u16)
__device__ __forceinline__ unsigned int bfpack(float a, float b) {
    return (__float_as_uint(a) >> 16) | (__float_as_uint(b) & 0xFFFF0000u);
}

// hi/lo split: hi = trunc-bf16(v); lo = trunc-bf16(v - hi).  Captures 2^-17 rel.
__device__ __forceinline__ void split4(const float4 v, uint2& hi, uint2& lo) {
    float hx = __uint_as_float(__float_as_uint(v.x) & 0xFFFF0000u);
    float hy = __uint_as_float(__float_as_uint(v.y) & 0xFFFF0000u);
    float hz = __uint_as_float(__float_as_uint(v.z) & 0xFFFF0000u);
    float hw = __uint_as_float(__float_as_uint(v.w) & 0xFFFF0000u);
    hi.x = bfpack(v.x, v.y); hi.y = bfpack(v.z, v.w);
    lo.x = bfpack(v.x - hx, v.y - hy); lo.y = bfpack(v.z - hz, v.w - hw);
}

union U8 { unsigned int u[4]; s16x8 v; };

// ---------------------------------------------------------------------------
// K1: qw = Q @ W (fp32 vector; only 0.27 G-MAC, not the bottleneck)
// ---------------------------------------------------------------------------
__global__ __launch_bounds__(256) void k1_qw(const float* __restrict__ q,
                                             const float* __restrict__ w,
                                             float* __restrict__ qw) {
    __shared__ float Ws[D_ * D_];
    const int tid = threadIdx.x;
    const int rowbase = blockIdx.x * 64;
    #pragma unroll
    for (int t = 0; t < 16; ++t) {
        int i4 = t * 256 + tid;
        ((float4*)Ws)[i4] = ((const float4*)w)[i4];
    }
    __syncthreads();
    const int mg = tid >> 4, cg = tid & 15;
    const int c0 = cg * 8;
    const float* qrow[4];
    #pragma unroll
    for (int i = 0; i < 4; ++i)
        qrow[i] = q + (size_t)(rowbase + mg * 4 + i) * D_;
    float acc[4][8];
    #pragma unroll
    for (int i = 0; i < 4; ++i)
        #pragma unroll
        for (int j = 0; j < 8; ++j) acc[i][j] = 0.0f;
    for (int d0 = 0; d0 < D_; d0 += 16) {
        float qr[4][16];
        #pragma unroll
        for (int i = 0; i < 4; ++i)
            #pragma unroll
            for (int c4 = 0; c4 < 4; ++c4)
                *(float4*)&qr[i][c4 * 4] = *(const float4*)(qrow[i] + d0 + c4 * 4);
        #pragma unroll
        for (int dd = 0; dd < 16; ++dd) {
            const int d = d0 + dd;
            float4 w0 = *(const float4*)&Ws[d * D_ + c0];
            float4 w1 = *(const float4*)&Ws[d * D_ + c0 + 4];
            #pragma unroll
            for (int i = 0; i < 4; ++i) {
                float a = qr[i][dd];
                acc[i][0] += a * w0.x; acc[i][1] += a * w0.y;
                acc[i][2] += a * w0.z; acc[i][3] += a * w0.w;
                acc[i][4] += a * w1.x; acc[i][5] += a * w1.y;
                acc[i][6] += a * w1.z; acc[i][7] += a * w1.w;
            }
        }
    }
    #pragma unroll
    for (int i = 0; i < 4; ++i) {
        float* dst = qw + (size_t)(rowbase + mg * 4 + i) * D_ + c0;
        *(float4*)dst       = make_float4(acc[i][0], acc[i][1], acc[i][2], acc[i][3]);
        *(float4*)(dst + 4) = make_float4(acc[i][4], acc[i][5], acc[i][6], acc[i][7]);
    }
}

// ---------------------------------------------------------------------------
// K2: S = qw @ key^T via hi/lo-split bf16 MFMA (fp32-grade precision) + online
// row (max, sumexp) stats.  Block = 32 q-rows x full 2048 cols. grid (64, B).
// Wave (mw,nw): rows mw*16+(quad*4+reg), cols per tile nw*32 + nf*16 + l15.
// key tile staged hi/lo in LDS, rows padded to 136 ushorts (b128 reads 2-way).
// ---------------------------------------------------------------------------
__global__ __launch_bounds__(256) void k2_score_stats(
        const float* __restrict__ qw, const float* __restrict__ key,
        float* __restrict__ S, float* __restrict__ m_ws, float* __restrict__ l_ws) {
    __shared__ unsigned short Khi[64 * 136];
    __shared__ unsigned short Klo[64 * 136];
    __shared__ float s_m[2][32], s_l[2][32];

    const int tid  = threadIdx.x;
    const int b    = blockIdx.y;
    const int m0   = blockIdx.x * 32;
    const int w    = tid >> 6, lane = tid & 63;
    const int mw   = w >> 1,  nw   = w & 1;
    const int quad = lane >> 4, l15 = lane & 15;

    // A-fragments (qw rows, hi/lo), loaded once, held in registers
    const float* arow = qw + ((size_t)b * SQ_ + m0 + mw * 16 + l15) * D_;
    s16x8 a_hi[4], a_lo[4];
    #pragma unroll
    for (int k0 = 0; k0 < 4; ++k0) {
        const float* p = arow + k0 * 32 + quad * 8;
        float4 v0 = *(const float4*)p;
        float4 v1 = *(const float4*)(p + 4);
        uint2 h0, l0, h1, l1;
        split4(v0, h0, l0); split4(v1, h1, l1);
        U8 H, L;
        H.u[0] = h0.x; H.u[1] = h0.y; H.u[2] = h1.x; H.u[3] = h1.y;
        L.u[0] = l0.x; L.u[1] = l0.y; L.u[2] = l1.x; L.u[3] = l1.y;
        a_hi[k0] = H.v; a_lo[k0] = L.v;
    }

    float rm[4], rl[4];
    #pragma unroll
    for (int r = 0; r < 4; ++r) { rm[r] = -1e30f; rl[r] = 0.0f; }

    const int rb0 = nw * 32 + l15, rb1 = nw * 32 + 16 + l15;

    for (int t = 0; t < SK_ / 64; ++t) {
        const int n0 = t * 64;
        __syncthreads();
        const float* Kg = key + ((size_t)b * SK_ + n0) * D_;
        #pragma unroll
        for (int it = 0; it < 8; ++it) {
            int idx = it * 256 + tid;
            int r = idx >> 5, c4 = idx & 31;
            float4 v = ((const float4*)(Kg + (size_t)r * D_))[c4];
            uint2 h, l; split4(v, h, l);
            unsigned int* ph = (unsigned int*)Khi + r * 68 + c4 * 2;
            unsigned int* pl = (unsigned int*)Klo + r * 68 + c4 * 2;
            ph[0] = h.x; ph[1] = h.y; pl[0] = l.x; pl[1] = l.y;
        }
        __syncthreads();

        f32x4 acc0 = {0.f, 0.f, 0.f, 0.f}, acc1 = {0.f, 0.f, 0.f, 0.f};
        #pragma unroll
        for (int k0 = 0; k0 < 4; ++k0) {
            int c8 = (k0 * 4 + quad) * 8;
            s16x8 bh0 = *(const s16x8*)&Khi[rb0 * 136 + c8];
            s16x8 bl0 = *(const s16x8*)&Klo[rb0 * 136 + c8];
            s16x8 bh1 = *(const s16x8*)&Khi[rb1 * 136 + c8];
            s16x8 bl1 = *(const s16x8*)&Klo[rb1 * 136 + c8];
            acc0 = mfma16(a_hi[k0], bh0, acc0);
            acc0 = mfma16(a_lo[k0], bh0, acc0);
            acc0 = mfma16(a_hi[k0], bl0, acc0);
            acc1 = mfma16(a_hi[k0], bh1, acc1);
            acc1 = mfma16(a_lo[k0], bh1, acc1);
            acc1 = mfma16(a_hi[k0], bl1, acc1);
        }

        // raw score store (C-layout: row = quad*4+reg, col = lane&15)
        float* Sp = S + ((size_t)b * SQ_ + m0 + mw * 16 + quad * 4) * SK_
                      + n0 + nw * 32 + l15;
        #pragma unroll
        for (int r = 0; r < 4; ++r) {
            Sp[(size_t)r * SK_]      = acc0[r];
            Sp[(size_t)r * SK_ + 16] = acc1[r];
        }

        // online (m,l) update per row
        #pragma unroll
        for (int r = 0; r < 4; ++r) {
            float tm = fmaxf(acc0[r], acc1[r]);
            tm = fmaxf(tm, __shfl_xor(tm, 1, 64));
            tm = fmaxf(tm, __shfl_xor(tm, 2, 64));
            tm = fmaxf(tm, __shfl_xor(tm, 4, 64));
            tm = fmaxf(tm, __shfl_xor(tm, 8, 64));
            float ts = __expf(acc0[r] - tm) + __expf(acc1[r] - tm);
            ts += __shfl_xor(ts, 1, 64);
            ts += __shfl_xor(ts, 2, 64);
            ts += __shfl_xor(ts, 4, 64);
            ts += __shfl_xor(ts, 8, 64);
            float nm = fmaxf(rm[r], tm);
            rl[r] = rl[r] * __expf(rm[r] - nm) + ts * __expf(tm - nm);
            rm[r] = nm;
        }
    }

    // merge the two column-half waves
    if (l15 == 0) {
        #pragma unroll
        for (int r = 0; r < 4; ++r) {
            s_m[nw][mw * 16 + quad * 4 + r] = rm[r];
            s_l[nw][mw * 16 + quad * 4 + r] = rl[r];
        }
    }
    __syncthreads();
    if (tid < 32) {
        float ma = s_m[0][tid], mb = s_m[1][tid];
        float M = fmaxf(ma, mb);
        float L = s_l[0][tid] * __expf(ma - M) + s_l[1][tid] * __expf(mb - M);
        m_ws[(size_t)b * SQ_ + m0 + tid] = M;
        l_ws[(size_t)b * SQ_ + m0 + tid] = L;
    }
}

// ---------------------------------------------------------------------------
// K3: normalize weight in place (w = exp(s-m)/l) + out = w @ V via bf16 MFMA.
// Block = 32 q-rows x 128 V-cols, K-chunks of 64. grid (64, B).
// P staged [32][72] bf16; V staged transposed [128][72] bf16 (B-operand needs
// k-contiguous per column).  Row padding keeps all b128 frag reads 2-way.
// ---------------------------------------------------------------------------
__global__ __launch_bounds__(256) void k3_pv(float* __restrict__ Wgt,
        const float* __restrict__ V, float* __restrict__ O,
        const float* __restrict__ m_ws, const float* __restrict__ l_ws) {
    __shared__ unsigned short Pt[32 * 72];
    __shared__ unsigned short Vt[128 * 72];

    const int tid  = threadIdx.x;
    const int b    = blockIdx.y;
    const int m0   = blockIdx.x * 32;
    const int w    = tid >> 6, lane = tid & 63;
    const int mw   = w >> 1,  nw   = w & 1;
    const int quad = lane >> 4, l15 = lane & 15;

    // P staging: thread -> (row pr, 2 float4 at col-block pc)
    const int pr = tid >> 3, pc = tid & 7;
    const float m_r  = m_ws[(size_t)b * SQ_ + m0 + pr];
    const float invl = 1.0f / l_ws[(size_t)b * SQ_ + m0 + pr];
    float* Prow = Wgt + ((size_t)b * SQ_ + m0 + pr) * SK_;

    // V staging: thread -> (n-quad vn4, 4 k-pairs at vk2)
    const int vn4 = tid >> 3, vk2 = tid & 7;
    const float* Vb = V + (size_t)b * SK_ * D_;

    f32x4 acc[4];
    #pragma unroll
    for (int nf = 0; nf < 4; ++nf) acc[nf] = (f32x4){0.f, 0.f, 0.f, 0.f};

    for (int kt = 0; kt < SK_; kt += 64) {
        __syncthreads();
        // ---- P: normalize, write weight out, stage bf16 ----
        #pragma unroll
        for (int e = 0; e < 2; ++e) {
            int c4 = pc * 2 + e;
            float4 s4 = ((const float4*)(Prow + kt))[c4];
            float4 p4;
            p4.x = __expf(s4.x - m_r) * invl;
            p4.y = __expf(s4.y - m_r) * invl;
            p4.z = __expf(s4.z - m_r) * invl;
            p4.w = __expf(s4.w - m_r) * invl;
            ((float4*)(Prow + kt))[c4] = p4;
            unsigned int* pp = (unsigned int*)Pt + pr * 36 + c4 * 2;
            pp[0] = bfpack(p4.x, p4.y);
            pp[1] = bfpack(p4.z, p4.w);
        }
        // ---- V: stage transposed [n][k], k-pairs packed ----
        #pragma unroll
        for (int i = 0; i < 4; ++i) {
            int kp = vk2 * 4 + i;
            const float* vp = Vb + (size_t)(kt + kp * 2) * D_ + vn4 * 4;
            float4 va  = *(const float4*)vp;
            float4 vb4 = *(const float4*)(vp + D_);
            unsigned int* qv = (unsigned int*)Vt;
            qv[(vn4 * 4 + 0) * 36 + kp] = bfpack(va.x, vb4.x);
            qv[(vn4 * 4 + 1) * 36 + kp] = bfpack(va.y, vb4.y);
            qv[(vn4 * 4 + 2) * 36 + kp] = bfpack(va.z, vb4.z);
            qv[(vn4 * 4 + 3) * 36 + kp] = bfpack(va.w, vb4.w);
        }
        __syncthreads();
        // ---- MFMA: 16x16x32, A = P rows, B = V cols ----
        #pragma unroll
        for (int k0 = 0; k0 < 2; ++k0) {
            int c8 = (k0 * 4 + quad) * 8;
            s16x8 af = *(const s16x8*)&Pt[(mw * 16 + l15) * 72 + c8];
            #pragma unroll
            for (int nf = 0; nf < 4; ++nf) {
                s16x8 bf = *(const s16x8*)&Vt[(nw * 64 + nf * 16 + l15) * 72 + c8];
                acc[nf] = mfma16(af, bf, acc[nf]);
            }
        }
    }

    float* Op = O + ((size_t)b * SQ_ + m0 + mw * 16 + quad * 4) * D_ + nw * 64 + l15;
    #pragma unroll
    for (int nf = 0; nf < 4; ++nf)
        #pragma unroll
        for (int r = 0; r < 4; ++r)
            Op[(size_t)r * D_ + nf * 16] = acc[nf][r];
}

extern "C" void kernel_launch(void* const* d_in, const int* in_sizes, int n_in,
                              void* d_out, int out_size, void* d_ws, size_t ws_size,
                              hipStream_t stream) {
    const float* q = (const float*)d_in[0];
    const float* k = (const float*)d_in[1];
    const float* v = (const float*)d_in[2];
    const float* w = (const float*)d_in[3];
    float* out    = (float*)d_out;
    float* weight = out + (size_t)B_ * SQ_ * D_;
    float* qw     = out;                       // scratch in out region (dead until k3)
    float* m_ws   = (float*)d_ws;              // [B*SQ]
    float* l_ws   = m_ws + (size_t)B_ * SQ_;   // [B*SQ]  (needs 128 KB ws)

    k1_qw<<<(B_ * SQ_) / 64, 256, 0, stream>>>(q, w, qw);
    k2_score_stats<<<dim3(SQ_ / 32, B_), 256, 0, stream>>>(qw, k, weight, m_ws, l_ws);
    k3_pv<<<dim3(SQ_ / 32, B_), 256, 0, stream>>>(weight, v, out, m_ws, l_ws);
}

// Round 3
// 384.283 us; speedup vs baseline: 1.2742x; 1.1509x over previous
//
#include <hip/hip_runtime.h>

#define B_  8
#define SQ_ 2048
#define SK_ 2048
#define D_  128

typedef float  f32x4 __attribute__((ext_vector_type(4)));
typedef short  s16x8 __attribute__((ext_vector_type(8)));
typedef __bf16 b16x8 __attribute__((ext_vector_type(8)));

__device__ __forceinline__ f32x4 mfma16(s16x8 a, s16x8 b, f32x4 c) {
    return __builtin_amdgcn_mfma_f32_16x16x32_bf16(
        __builtin_bit_cast(b16x8, a), __builtin_bit_cast(b16x8, b), c, 0, 0, 0);
}

// truncate-to-bf16 pack of two floats (a -> low u16, b -> high u16)
__device__ __forceinline__ unsigned int bfpack(float a, float b) {
    return (__float_as_uint(a) >> 16) | (__float_as_uint(b) & 0xFFFF0000u);
}

// hi/lo split: hi = trunc-bf16(v); lo = trunc-bf16(v - hi).
__device__ __forceinline__ void split4(const float4 v, uint2& hi, uint2& lo) {
    float hx = __uint_as_float(__float_as_uint(v.x) & 0xFFFF0000u);
    float hy = __uint_as_float(__float_as_uint(v.y) & 0xFFFF0000u);
    float hz = __uint_as_float(__float_as_uint(v.z) & 0xFFFF0000u);
    float hw = __uint_as_float(__float_as_uint(v.w) & 0xFFFF0000u);
    hi.x = bfpack(v.x, v.y); hi.y = bfpack(v.z, v.w);
    lo.x = bfpack(v.x - hx, v.y - hy); lo.y = bfpack(v.z - hz, v.w - hw);
}

union U8 { unsigned int u[4]; s16x8 v; };

// ---------------------------------------------------------------------------
// K1: qw = Q @ W (fp32 vector; 0.27 G-MAC, not the bottleneck)
// ---------------------------------------------------------------------------
__global__ __launch_bounds__(256) void k1_qw(const float* __restrict__ q,
                                             const float* __restrict__ w,
                                             float* __restrict__ qw) {
    __shared__ float Ws[D_ * D_];
    const int tid = threadIdx.x;
    const int rowbase = blockIdx.x * 64;
    #pragma unroll
    for (int t = 0; t < 16; ++t) {
        int i4 = t * 256 + tid;
        ((float4*)Ws)[i4] = ((const float4*)w)[i4];
    }
    __syncthreads();
    const int mg = tid >> 4, cg = tid & 15;
    const int c0 = cg * 8;
    const float* qrow[4];
    #pragma unroll
    for (int i = 0; i < 4; ++i)
        qrow[i] = q + (size_t)(rowbase + mg * 4 + i) * D_;
    float acc[4][8];
    #pragma unroll
    for (int i = 0; i < 4; ++i)
        #pragma unroll
        for (int j = 0; j < 8; ++j) acc[i][j] = 0.0f;
    for (int d0 = 0; d0 < D_; d0 += 16) {
        float qr[4][16];
        #pragma unroll
        for (int i = 0; i < 4; ++i)
            #pragma unroll
            for (int c4 = 0; c4 < 4; ++c4)
                *(float4*)&qr[i][c4 * 4] = *(const float4*)(qrow[i] + d0 + c4 * 4);
        #pragma unroll
        for (int dd = 0; dd < 16; ++dd) {
            const int d = d0 + dd;
            float4 w0 = *(const float4*)&Ws[d * D_ + c0];
            float4 w1 = *(const float4*)&Ws[d * D_ + c0 + 4];
            #pragma unroll
            for (int i = 0; i < 4; ++i) {
                float a = qr[i][dd];
                acc[i][0] += a * w0.x; acc[i][1] += a * w0.y;
                acc[i][2] += a * w0.z; acc[i][3] += a * w0.w;
                acc[i][4] += a * w1.x; acc[i][5] += a * w1.y;
                acc[i][6] += a * w1.z; acc[i][7] += a * w1.w;
            }
        }
    }
    #pragma unroll
    for (int i = 0; i < 4; ++i) {
        float* dst = qw + (size_t)(rowbase + mg * 4 + i) * D_ + c0;
        *(float4*)dst       = make_float4(acc[i][0], acc[i][1], acc[i][2], acc[i][3]);
        *(float4*)(dst + 4) = make_float4(acc[i][4], acc[i][5], acc[i][6], acc[i][7]);
    }
}

// ---------------------------------------------------------------------------
// K2: S-tile = qw-tile @ key-tile^T, hi/lo-split bf16 MFMA.
// grid (SK/64, SQ/64, B) = 8192 blocks, 4 waves (mw,nw in 2x2), 64x64 tile.
// Full D=128 reduction: key tile staged hi/lo in LDS once (1 barrier/block);
// qw fragments loaded straight into registers.
// ---------------------------------------------------------------------------
__global__ __launch_bounds__(256) void k2_score(
        const float* __restrict__ qw, const float* __restrict__ key,
        float* __restrict__ S) {
    __shared__ unsigned short Khi[64 * 136];
    __shared__ unsigned short Klo[64 * 136];

    const int tid  = threadIdx.x;
    const int b    = blockIdx.z;
    const int m0   = blockIdx.y * 64;
    const int n0   = blockIdx.x * 64;
    const int w    = tid >> 6, lane = tid & 63;
    const int mw   = w >> 1,  nw   = w & 1;
    const int quad = lane >> 4, l15 = lane & 15;

    // stage K-tile hi/lo (64 rows x 128 feat)
    #pragma unroll
    for (int it = 0; it < 8; ++it) {
        int idx = it * 256 + tid;
        int r = idx >> 5, c4 = idx & 31;
        float4 v = ((const float4*)(key + ((size_t)b * SK_ + n0 + r) * D_))[c4];
        uint2 h, l; split4(v, h, l);
        unsigned int* ph = (unsigned int*)Khi + r * 68 + c4 * 2;
        unsigned int* pl = (unsigned int*)Klo + r * 68 + c4 * 2;
        ph[0] = h.x; ph[1] = h.y; pl[0] = l.x; pl[1] = l.y;
    }

    // A fragments: 2 row-tiles x 4 k-steps, hi/lo (registers)
    s16x8 a_hi[2][4], a_lo[2][4];
    #pragma unroll
    for (int rt = 0; rt < 2; ++rt) {
        const float* ar = qw + ((size_t)b * SQ_ + m0 + mw * 32 + rt * 16 + l15) * D_;
        #pragma unroll
        for (int k0 = 0; k0 < 4; ++k0) {
            const float* p = ar + k0 * 32 + quad * 8;
            float4 v0 = *(const float4*)p;
            float4 v1 = *(const float4*)(p + 4);
            uint2 h0, l0, h1, l1;
            split4(v0, h0, l0); split4(v1, h1, l1);
            U8 H, L;
            H.u[0] = h0.x; H.u[1] = h0.y; H.u[2] = h1.x; H.u[3] = h1.y;
            L.u[0] = l0.x; L.u[1] = l0.y; L.u[2] = l1.x; L.u[3] = l1.y;
            a_hi[rt][k0] = H.v; a_lo[rt][k0] = L.v;
        }
    }
    __syncthreads();

    f32x4 acc[2][2];
    #pragma unroll
    for (int rt = 0; rt < 2; ++rt)
        #pragma unroll
        for (int ct = 0; ct < 2; ++ct) acc[rt][ct] = (f32x4){0.f, 0.f, 0.f, 0.f};

    #pragma unroll
    for (int k0 = 0; k0 < 4; ++k0) {
        const int c8 = (k0 * 4 + quad) * 8;
        s16x8 bh[2], bl[2];
        #pragma unroll
        for (int ct = 0; ct < 2; ++ct) {
            int rb = nw * 32 + ct * 16 + l15;
            bh[ct] = *(const s16x8*)&Khi[rb * 136 + c8];
            bl[ct] = *(const s16x8*)&Klo[rb * 136 + c8];
        }
        #pragma unroll
        for (int rt = 0; rt < 2; ++rt)
            #pragma unroll
            for (int ct = 0; ct < 2; ++ct) {
                acc[rt][ct] = mfma16(a_hi[rt][k0], bh[ct], acc[rt][ct]);
                acc[rt][ct] = mfma16(a_lo[rt][k0], bh[ct], acc[rt][ct]);
                acc[rt][ct] = mfma16(a_hi[rt][k0], bl[ct], acc[rt][ct]);
            }
    }

    // store (C-layout: row = quad*4+r, col = l15)
    #pragma unroll
    for (int rt = 0; rt < 2; ++rt) {
        float* Sp = S + ((size_t)b * SQ_ + m0 + mw * 32 + rt * 16 + quad * 4) * SK_
                      + n0 + nw * 32 + l15;
        #pragma unroll
        for (int r = 0; r < 4; ++r)
            #pragma unroll
            for (int ct = 0; ct < 2; ++ct)
                Sp[(size_t)r * SK_ + ct * 16] = acc[rt][ct][r];
    }
}

// ---------------------------------------------------------------------------
// K2b: per-row (max, sumexp) from raw S.  One wave per row, coalesced float4.
// grid = B*SQ/4 blocks of 256.
// ---------------------------------------------------------------------------
__global__ __launch_bounds__(256) void k2b_stats(const float* __restrict__ S,
        float* __restrict__ m_ws, float* __restrict__ l_ws) {
    const int row  = blockIdx.x * 4 + (threadIdx.x >> 6);
    const int lane = threadIdx.x & 63;
    const float4* p = (const float4*)(S + (size_t)row * SK_);
    float4 x[8];
    #pragma unroll
    for (int i = 0; i < 8; ++i) x[i] = p[i * 64 + lane];

    float m = -1e30f;
    #pragma unroll
    for (int i = 0; i < 8; ++i)
        m = fmaxf(m, fmaxf(fmaxf(x[i].x, x[i].y), fmaxf(x[i].z, x[i].w)));
    #pragma unroll
    for (int off = 32; off; off >>= 1) m = fmaxf(m, __shfl_xor(m, off, 64));

    float s = 0.f;
    #pragma unroll
    for (int i = 0; i < 8; ++i)
        s += __expf(x[i].x - m) + __expf(x[i].y - m) +
             __expf(x[i].z - m) + __expf(x[i].w - m);
    #pragma unroll
    for (int off = 32; off; off >>= 1) s += __shfl_xor(s, off, 64);

    if (lane == 0) {
        m_ws[row] = m;
        l_ws[row] = s;
    }
}

// ---------------------------------------------------------------------------
// K3: normalize weight in place + out = w @ V via bf16 MFMA.
// Block = 16 q-rows x 128 V-cols, K-chunks of 64.  grid (SQ/16, B) = 1024.
// Waves are column groups (w*32); all share the 16 A-rows.
// ---------------------------------------------------------------------------
__global__ __launch_bounds__(256) void k3_pv(float* __restrict__ Wgt,
        const float* __restrict__ V, float* __restrict__ O,
        const float* __restrict__ m_ws, const float* __restrict__ l_ws) {
    __shared__ unsigned short Pt[16 * 72];
    __shared__ unsigned short Vt[128 * 72];

    const int tid  = threadIdx.x;
    const int b    = blockIdx.y;
    const int m0   = blockIdx.x * 16;
    const int w    = tid >> 6, lane = tid & 63;
    const int quad = lane >> 4, l15 = lane & 15;

    // P staging: thread -> (row pr, float4 col pc)
    const int pr = tid >> 4, pc = tid & 15;
    const float m_r  = m_ws[(size_t)b * SQ_ + m0 + pr];
    const float invl = 1.0f / l_ws[(size_t)b * SQ_ + m0 + pr];
    float* Prow = Wgt + ((size_t)b * SQ_ + m0 + pr) * SK_;

    // V staging: thread -> (n-quad vn4, 4 k-pairs at vk2)
    const int vn4 = tid >> 3, vk2 = tid & 7;
    const float* Vb = V + (size_t)b * SK_ * D_;

    f32x4 acc[2];
    acc[0] = (f32x4){0.f, 0.f, 0.f, 0.f};
    acc[1] = (f32x4){0.f, 0.f, 0.f, 0.f};

    for (int kt = 0; kt < SK_; kt += 64) {
        __syncthreads();
        // ---- P: normalize, write weight out, stage bf16 ----
        {
            float4 s4 = ((const float4*)(Prow + kt))[pc];
            float4 p4;
            p4.x = __expf(s4.x - m_r) * invl;
            p4.y = __expf(s4.y - m_r) * invl;
            p4.z = __expf(s4.z - m_r) * invl;
            p4.w = __expf(s4.w - m_r) * invl;
            ((float4*)(Prow + kt))[pc] = p4;
            unsigned int* pp = (unsigned int*)Pt + pr * 36 + pc * 2;
            pp[0] = bfpack(p4.x, p4.y);
            pp[1] = bfpack(p4.z, p4.w);
        }
        // ---- V: stage transposed [n][k], k-pairs packed ----
        #pragma unroll
        for (int i = 0; i < 4; ++i) {
            int kp = vk2 * 4 + i;
            const float* vp = Vb + (size_t)(kt + kp * 2) * D_ + vn4 * 4;
            float4 va  = *(const float4*)vp;
            float4 vb4 = *(const float4*)(vp + D_);
            unsigned int* qv = (unsigned int*)Vt;
            qv[(vn4 * 4 + 0) * 36 + kp] = bfpack(va.x, vb4.x);
            qv[(vn4 * 4 + 1) * 36 + kp] = bfpack(va.y, vb4.y);
            qv[(vn4 * 4 + 2) * 36 + kp] = bfpack(va.z, vb4.z);
            qv[(vn4 * 4 + 3) * 36 + kp] = bfpack(va.w, vb4.w);
        }
        __syncthreads();
        // ---- MFMA: A = P rows (shared), B = V col group of this wave ----
        #pragma unroll
        for (int k0 = 0; k0 < 2; ++k0) {
            int c8 = (k0 * 4 + quad) * 8;
            s16x8 af = *(const s16x8*)&Pt[l15 * 72 + c8];
            #pragma unroll
            for (int nf = 0; nf < 2; ++nf) {
                s16x8 bf = *(const s16x8*)&Vt[(w * 32 + nf * 16 + l15) * 72 + c8];
                acc[nf] = mfma16(af, bf, acc[nf]);
            }
        }
    }

    float* Op = O + ((size_t)b * SQ_ + m0 + quad * 4) * D_ + w * 32 + l15;
    #pragma unroll
    for (int nf = 0; nf < 2; ++nf)
        #pragma unroll
        for (int r = 0; r < 4; ++r)
            Op[(size_t)r * D_ + nf * 16] = acc[nf][r];
}

extern "C" void kernel_launch(void* const* d_in, const int* in_sizes, int n_in,
                              void* d_out, int out_size, void* d_ws, size_t ws_size,
                              hipStream_t stream) {
    const float* q = (const float*)d_in[0];
    const float* k = (const float*)d_in[1];
    const float* v = (const float*)d_in[2];
    const float* w = (const float*)d_in[3];
    float* out    = (float*)d_out;
    float* weight = out + (size_t)B_ * SQ_ * D_;
    float* qw     = out;                       // scratch in out region (dead until k3)
    float* m_ws   = (float*)d_ws;              // [B*SQ]
    float* l_ws   = m_ws + (size_t)B_ * SQ_;   // [B*SQ]

    k1_qw<<<(B_ * SQ_) / 64, 256, 0, stream>>>(q, w, qw);
    k2_score<<<dim3(SK_ / 64, SQ_ / 64, B_), 256, 0, stream>>>(qw, k, weight);
    k2b_stats<<<(B_ * SQ_) / 4, 256, 0, stream>>>(weight, m_ws, l_ws);
    k3_pv<<<dim3(SQ_ / 16, B_), 256, 0, stream>>>(weight, v, out, m_ws, l_ws);
}